// Round 13
// baseline (141.529 us; speedup 1.0000x reference)
//
#include <hip/hip_runtime.h>

#define S_LEN 1024

typedef unsigned short u16;
using bf16x8 = __attribute__((ext_vector_type(8))) short;
using f32x4  = __attribute__((ext_vector_type(4))) float;
using u16x8  = __attribute__((ext_vector_type(8))) unsigned short;
using u16x4  = __attribute__((ext_vector_type(4))) unsigned short;
using u32x4  = __attribute__((ext_vector_type(4))) unsigned int;

__device__ __forceinline__ float bf2f(u16 b) {
  unsigned int u = ((unsigned int)b) << 16;
  return __builtin_bit_cast(float, u);
}
__device__ __forceinline__ u16 f2bf(float f) {
  unsigned int u = __builtin_bit_cast(unsigned int, f);
  unsigned int r = u + 0x7fffu + ((u >> 16) & 1u);
  return (u16)(r >> 16);
}
// packed RNE f32x2 -> bf16x2 (same rounding as f2bf)
__device__ __forceinline__ unsigned int cvtpk(float lo, float hi) {
  unsigned int r;
  asm("v_cvt_pk_bf16_f32 %0, %1, %2" : "=v"(r) : "v"(lo), "v"(hi));
  return r;
}
__device__ __forceinline__ float fmax3(float a, float b, float c) {
  return fmaxf(fmaxf(a, b), c);  // fuses to v_max3_f32
}

using gas_p = const __attribute__((address_space(1))) void*;
using las_p = __attribute__((address_space(3))) void*;
__device__ __forceinline__ void gload16(const void* g, void* l) {
  __builtin_amdgcn_global_load_lds((gas_p)g, (las_p)l, 16, 0, 0);
}

// ---------------- merged f32 -> bf16 conversion (weights + rel only; x is
// consumed as f32 directly by the QKV GEMM) ----------------
__global__ __launch_bounds__(256) void cvt_all(
    const float* __restrict__ wqkv, const float* __restrict__ wout,
    const float* __restrict__ wpos, const float* __restrict__ rel,
    u16* __restrict__ wqkvb, u16* __restrict__ woutb,
    u16* __restrict__ wposb, u16* __restrict__ relb) {
  int blk = blockIdx.x;
  const float* src; u16* dst; int base;
  if (blk < 3072)      { src = wqkv; dst = wqkvb; base = blk; }
  else if (blk < 4096) { src = wout; dst = woutb; base = blk - 3072; }
  else if (blk < 5120) { src = wpos; dst = wposb; base = blk - 4096; }
  else                 { src = rel;  dst = relb;  base = blk - 5120; }
  int i = (base * 256 + threadIdx.x) * 4;
  float4 v = *(const float4*)(src + i);
  u16x4 o;
  o.x = f2bf(v.x); o.y = f2bf(v.y); o.z = f2bf(v.z); o.w = f2bf(v.w);
  *(u16x4*)(dst + i) = o;
}

// ---------------- fused QKV GEMM (768 blocks) + rel GEMM (128 blocks) ----------------
// QKV path stages x as FP32 (XOR-swizzled: LDS linear dest, global source
// block' = blk ^ (row&7), read with same XOR -> conflict-free f32 frag reads),
// converting to bf16 at LDS->reg via v_cvt_pk_bf16_f32 (same RNE as f2bf).
// Epilogue: qc=(q+u)/8, qp=(q+v)/8; k cols -> qkvb 1024..2047; v cols
// transposed into the q-column hole (cols 0..1023).
__global__ __launch_bounds__(256) void gemm_qkv_rel(
    const float* __restrict__ xf, const u16* __restrict__ wqkvb,
    u16* __restrict__ qkvb, u16* __restrict__ qc, u16* __restrict__ qp,
    const float* __restrict__ uvec, const float* __restrict__ vvec,
    const u16* __restrict__ relb, const u16* __restrict__ wposb,
    u16* __restrict__ relproj) {
  __shared__ __align__(16) float Asf[2][4096];   // 128 rows x 32 f32 (16KB/buf)
  __shared__ __align__(16) u16 Ws[2][128 * 32];
  const int t = threadIdx.x;
  const int w = t >> 6, l = t & 63;
  const int lr = l & 15, lg = l >> 4;
  const int flat = blockIdx.x;

  if (flat < 768) {
    // ---- QKV path: M=4096, N=3072, K=1024, BM=128, MI=4 ----
    const int xcd = flat & 7, idx = flat >> 3;
    const int bm = (xcd & 3) * 8 + (idx & 7);
    const int bn = (xcd >> 2) * 12 + (idx >> 3);
    const int wr = (w >> 1) * 64, wc = (w & 1) * 64;
    f32x4 acc[4][4];
#pragma unroll
    for (int mi = 0; mi < 4; ++mi)
#pragma unroll
      for (int ni = 0; ni < 4; ++ni) acc[mi][ni] = (f32x4){0.f, 0.f, 0.f, 0.f};
    const float* Ab = xf + (size_t)bm * 128 * 1024;
    const u16* Wb = wqkvb + (size_t)bn * 128 * 1024;
    auto stage = [&](int k0, int buf) {
      // A: f32, 4 chunks; global block pre-swizzled so LDS linear slot
      // (row, seg) holds quad seg^(row&7)
#pragma unroll
      for (int i = 0; i < 4; ++i) {
        int c = i * 256 + t;
        int row = c >> 3, seg = c & 7;
        gload16(Ab + (size_t)row * 1024 + k0 + ((seg ^ (row & 7)) * 4),
                &Asf[buf][c * 4]);
      }
#pragma unroll
      for (int i = 0; i < 2; ++i) {
        int c = i * 256 + t;
        gload16(Wb + (size_t)(c >> 2) * 1024 + k0 + (c & 3) * 8, &Ws[buf][c * 8]);
      }
    };
    stage(0, 0);
    __syncthreads();
    for (int k0 = 0; k0 < 1024; k0 += 32) {
      const int cur = (k0 >> 5) & 1;
      if (k0 + 32 < 1024) stage(k0 + 32, cur ^ 1);
      bf16x8 af[4], wf[4];
#pragma unroll
      for (int mi = 0; mi < 4; ++mi) {
        int r = wr + mi * 16 + lr;
        int sw = r & 7;
        const float* base = &Asf[cur][r * 32];
        f32x4 lo = *(const f32x4*)&base[((2 * lg) ^ sw) * 4];
        f32x4 hi = *(const f32x4*)&base[((2 * lg + 1) ^ sw) * 4];
        u32x4 pw;
        pw[0] = cvtpk(lo[0], lo[1]); pw[1] = cvtpk(lo[2], lo[3]);
        pw[2] = cvtpk(hi[0], hi[1]); pw[3] = cvtpk(hi[2], hi[3]);
        af[mi] = __builtin_bit_cast(bf16x8, pw);
      }
#pragma unroll
      for (int ni = 0; ni < 4; ++ni)
        wf[ni] = *(const bf16x8*)&Ws[cur][(wc + ni * 16 + lr) * 32 + lg * 8];
      __builtin_amdgcn_s_setprio(1);
#pragma unroll
      for (int mi = 0; mi < 4; ++mi)
#pragma unroll
        for (int ni = 0; ni < 4; ++ni)
          acc[mi][ni] = __builtin_amdgcn_mfma_f32_16x16x32_bf16(af[mi], wf[ni], acc[mi][ni], 0, 0, 0);
      __builtin_amdgcn_s_setprio(0);
      __syncthreads();
    }
#pragma unroll
    for (int mi = 0; mi < 4; ++mi)
#pragma unroll
      for (int ni = 0; ni < 4; ++ni) {
        int col = bn * 128 + wc + ni * 16 + lr;
        if (col < 1024) {
          float uu = uvec[col], vv = vvec[col];
#pragma unroll
          for (int g = 0; g < 4; ++g) {
            int row = bm * 128 + wr + mi * 16 + lg * 4 + g;
            qc[(size_t)row * 1024 + col] = f2bf((acc[mi][ni][g] + uu) * 0.125f);
            qp[(size_t)row * 1024 + col] = f2bf((acc[mi][ni][g] + vv) * 0.125f);
          }
        } else if (col < 2048) {
#pragma unroll
          for (int g = 0; g < 4; ++g) {
            int row = bm * 128 + wr + mi * 16 + lg * 4 + g;
            qkvb[(size_t)row * 3072 + col] = f2bf(acc[mi][ni][g]);
          }
        } else {
          int row0 = bm * 128 + wr + mi * 16 + lg * 4;
          int vrow = (row0 >> 10) * 1024 + (col - 2048);
          u16x4 tmp;
#pragma unroll
          for (int g = 0; g < 4; ++g) tmp[g] = f2bf(acc[mi][ni][g]);
          *(u16x4*)&qkvb[(size_t)vrow * 3072 + (row0 & 1023)] = tmp;
        }
      }
  } else {
    // ---- rel path: relproj = relb @ wposb^T, M=N=K=1024, BM=64, MI=2 ----
    const int r = flat - 768;
    const int bm = r & 15, bn = r >> 4;
    const int wr = (w >> 1) * 32, wc = (w & 1) * 64;
    f32x4 acc[2][4];
#pragma unroll
    for (int mi = 0; mi < 2; ++mi)
#pragma unroll
      for (int ni = 0; ni < 4; ++ni) acc[mi][ni] = (f32x4){0.f, 0.f, 0.f, 0.f};
    const u16* Ab = relb + (size_t)bm * 64 * 1024;
    const u16* Wb = wposb + (size_t)bn * 128 * 1024;
    auto stage = [&](int k0, int buf) {
      u16* As = (u16*)&Asf[buf][0];
      {
        int c = t;
        gload16(Ab + (size_t)(c >> 2) * 1024 + k0 + (c & 3) * 8, &As[c * 8]);
      }
#pragma unroll
      for (int i = 0; i < 2; ++i) {
        int c = i * 256 + t;
        gload16(Wb + (size_t)(c >> 2) * 1024 + k0 + (c & 3) * 8, &Ws[buf][c * 8]);
      }
    };
    stage(0, 0);
    __syncthreads();
    for (int k0 = 0; k0 < 1024; k0 += 32) {
      const int cur = (k0 >> 5) & 1;
      if (k0 + 32 < 1024) stage(k0 + 32, cur ^ 1);
      const u16* As = (const u16*)&Asf[cur][0];
      bf16x8 af[2], wf[4];
#pragma unroll
      for (int mi = 0; mi < 2; ++mi)
        af[mi] = *(const bf16x8*)&As[(wr + mi * 16 + lr) * 32 + lg * 8];
#pragma unroll
      for (int ni = 0; ni < 4; ++ni)
        wf[ni] = *(const bf16x8*)&Ws[cur][(wc + ni * 16 + lr) * 32 + lg * 8];
      __builtin_amdgcn_s_setprio(1);
#pragma unroll
      for (int mi = 0; mi < 2; ++mi)
#pragma unroll
        for (int ni = 0; ni < 4; ++ni)
          acc[mi][ni] = __builtin_amdgcn_mfma_f32_16x16x32_bf16(af[mi], wf[ni], acc[mi][ni], 0, 0, 0);
      __builtin_amdgcn_s_setprio(0);
      __syncthreads();
    }
#pragma unroll
    for (int mi = 0; mi < 2; ++mi)
#pragma unroll
      for (int ni = 0; ni < 4; ++ni) {
        int col = bn * 128 + wc + ni * 16 + lr;
#pragma unroll
        for (int g = 0; g < 4; ++g) {
          int row = bm * 64 + wr + mi * 16 + lg * 4 + g;
          relproj[(size_t)row * 1024 + col] = f2bf(acc[mi][ni][g]);
        }
      }
  }
}

// ---------------- out-proj GEMM: out = attno @ woutb^T (f32 out) ----------------
__global__ __launch_bounds__(256) void gemm_out(const u16* __restrict__ A,
    const u16* __restrict__ W, float* __restrict__ Yf) {
  __shared__ __align__(16) u16 As[2][64 * 32];
  __shared__ __align__(16) u16 Ws[2][128 * 32];
  const int t = threadIdx.x;
  const int w = t >> 6, l = t & 63;
  const int lr = l & 15, lg = l >> 4;
  const int flat = (int)blockIdx.y * 64 + (int)blockIdx.x;
  const int bn = flat & 7, bm = flat >> 3;
  const int wr = (w >> 1) * 32, wc = (w & 1) * 64;
  f32x4 acc[2][4];
#pragma unroll
  for (int mi = 0; mi < 2; ++mi)
#pragma unroll
    for (int ni = 0; ni < 4; ++ni) acc[mi][ni] = (f32x4){0.f, 0.f, 0.f, 0.f};
  const u16* Ab = A + (size_t)bm * 64 * 1024;
  const u16* Wb = W + (size_t)bn * 128 * 1024;
  auto stage = [&](int k0, int buf) {
    {
      int c = t;
      gload16(Ab + (size_t)(c >> 2) * 1024 + k0 + (c & 3) * 8, &As[buf][c * 8]);
    }
#pragma unroll
    for (int i = 0; i < 2; ++i) {
      int c = i * 256 + t;
      gload16(Wb + (size_t)(c >> 2) * 1024 + k0 + (c & 3) * 8, &Ws[buf][c * 8]);
    }
  };
  stage(0, 0);
  __syncthreads();
  for (int k0 = 0; k0 < 1024; k0 += 32) {
    const int cur = (k0 >> 5) & 1;
    if (k0 + 32 < 1024) stage(k0 + 32, cur ^ 1);
    bf16x8 af[2], wf[4];
#pragma unroll
    for (int mi = 0; mi < 2; ++mi)
      af[mi] = *(const bf16x8*)&As[cur][(wr + mi * 16 + lr) * 32 + lg * 8];
#pragma unroll
    for (int ni = 0; ni < 4; ++ni)
      wf[ni] = *(const bf16x8*)&Ws[cur][(wc + ni * 16 + lr) * 32 + lg * 8];
    __builtin_amdgcn_s_setprio(1);
#pragma unroll
    for (int mi = 0; mi < 2; ++mi)
#pragma unroll
      for (int ni = 0; ni < 4; ++ni)
        acc[mi][ni] = __builtin_amdgcn_mfma_f32_16x16x32_bf16(af[mi], wf[ni], acc[mi][ni], 0, 0, 0);
    __builtin_amdgcn_s_setprio(0);
    __syncthreads();
  }
#pragma unroll
  for (int mi = 0; mi < 2; ++mi)
#pragma unroll
    for (int ni = 0; ni < 4; ++ni) {
      int col = bn * 128 + wc + ni * 16 + lr;
#pragma unroll
      for (int g = 0; g < 4; ++g) {
        int row = bm * 64 + wr + mi * 16 + lg * 4 + g;
        Yf[(size_t)row * 1024 + col] = acc[mi][ni][g];
      }
    }
}

// ---------------- fused causal attention with TXL rel-shift (v9, proven) ----------------
__global__ __launch_bounds__(256) void attn_fwd(
    const u16* __restrict__ qcb, const u16* __restrict__ qpb,
    const u16* __restrict__ qkv, const u16* __restrict__ relp,
    u16* __restrict__ out) {
  __shared__ __align__(16) u16 Ksb[2][4096];
  __shared__ __align__(16) u16 Vtb[2][4096];
  __shared__ __align__(16) u16 Rs3[3][4096];
  __shared__ __align__(16) float Psf[4][16][68];

  const int flat = (int)blockIdx.y * 8 + (int)blockIdx.x;
  const int wg = (flat & 7) * 64 + (flat >> 3);
  const int sub = wg & 7;
  const int bh = wg >> 3;
  const int b = bh >> 4, h = bh & 15;
  const int t = threadIdx.x;
  const int w = t >> 6, l = t & 63;
  const int lr = l & 15, lg = l >> 4;

  const u16* Kg = qkv + (size_t)b * S_LEN * 3072 + 1024 + h * 64;
  const u16* Vg = qkv + (size_t)bh * 64 * 3072;  // V^T rows in the q-hole
  const u16* Rg = relp + h * 64;

  int gl4[4], cg[4];
#pragma unroll
  for (int g = 0; g < 4; ++g) {
    int ql = lg * 4 + g;
    gl4[g] = (l & 48) | ((lr - ql - 1) & 15);
    cg[g] = (lr > ql) ? 1 : 0;
  }

  for (int half = 0; half < 2; ++half) {
    const int qt = half ? sub : (15 - sub);
    const int i0 = qt * 64;
    const int nt = qt + 1;

    bf16x8 qcf[2], qpf[2];
    {
      size_t qoff = (size_t)(b * S_LEN + i0 + w * 16 + lr) * 1024 + h * 64;
      qcf[0] = *(const bf16x8*)(qcb + qoff + lg * 8);
      qcf[1] = *(const bf16x8*)(qcb + qoff + 32 + lg * 8);
      qpf[0] = *(const bf16x8*)(qpb + qoff + lg * 8);
      qpf[1] = *(const bf16x8*)(qpb + qoff + 32 + lg * 8);
    }

    auto stage_k = [&](int j0s, int buf) {
#pragma unroll
      for (int i = 0; i < 2; ++i) {
        int bK = i * 4 + w;
        int ttk = bK >> 1, kc = bK & 1;
        gload16(Kg + (size_t)(j0s + ttk * 16 + lr) * 3072 + kc * 32 + lg * 8,
                &Ksb[buf][bK * 512 + l * 8]);
      }
    };
    auto stage_v = [&](int j0s, int buf) {
#pragma unroll
      for (int i = 0; i < 2; ++i) {
        int bV = i * 4 + w;
        int dt = bV >> 1, kc = bV & 1;
        gload16(Vg + (size_t)(dt * 16 + lr) * 3072 + j0s + kc * 32 + lg * 8,
                &Vtb[buf][bV * 512 + l * 8]);
      }
    };
    auto stage_rchunk = [&](int Gloc, int slot) {
      int Gg = 15 - qt + Gloc;
#pragma unroll
      for (int i = 0; i < 2; ++i) {
        int bR = i * 4 + w;
        int btc = bR >> 1, kc = bR & 1;
        int r = Gg * 64 + btc * 16 + lr;
        r = r > S_LEN - 1 ? S_LEN - 1 : r;
        gload16(Rg + (size_t)r * 1024 + kc * 32 + lg * 8,
                &Rs3[slot][bR * 512 + l * 8]);
      }
    };

    float m_run = 0.f, l_run = 0.f;   // T13: finite baseline (scores ~ +-12)
    f32x4 o_acc[4];
#pragma unroll
    for (int dt = 0; dt < 4; ++dt) o_acc[dt] = (f32x4){0.f, 0.f, 0.f, 0.f};

    stage_k(0, 0);
    stage_v(0, 0);
    stage_rchunk(0, 0);
    stage_rchunk(1, 1);
    __syncthreads();

    int sA = 0, sB = 1, sC = 2;
    for (int kt = 0; kt < nt; ++kt) {
      const int cur = kt & 1, nxt = cur ^ 1;
      const int j0 = kt * 64;
      const int have_nxt = (kt + 1 < nt);
      if (have_nxt) {
        stage_k(j0 + 64, nxt);
        stage_v(j0 + 64, nxt);
        stage_rchunk(kt + 2, sC);
      }

      // ---- Sc = qc @ K^T ----
      f32x4 sc[4];
      __builtin_amdgcn_s_setprio(1);
#pragma unroll
      for (int tt = 0; tt < 4; ++tt) {
        sc[tt] = (f32x4){0.f, 0.f, 0.f, 0.f};
#pragma unroll
        for (int kc = 0; kc < 2; ++kc) {
          bf16x8 kf = *(const bf16x8*)&Ksb[cur][(tt * 2 + kc) * 512 + l * 8];
          sc[tt] = __builtin_amdgcn_mfma_f32_16x16x32_bf16(qcf[kc], kf, sc[tt], 0, 0, 0);
        }
      }
      // ---- Sp band (5 tiles per wave) ----
      f32x4 sp[5];
#pragma unroll
      for (int u5 = 0; u5 < 5; ++u5) {
        int bt = 3 - w + u5;
        const u16* rb = (bt & 4) ? &Rs3[sB][0] : &Rs3[sA][0];
        int btc = bt & 3;
        sp[u5] = (f32x4){0.f, 0.f, 0.f, 0.f};
#pragma unroll
        for (int kc = 0; kc < 2; ++kc) {
          bf16x8 rf = *(const bf16x8*)&rb[(btc * 2 + kc) * 512 + l * 8];
          sp[u5] = __builtin_amdgcn_mfma_f32_16x16x32_bf16(qpf[kc], rf, sp[u5], 0, 0, 0);
        }
      }
      __builtin_amdgcn_s_setprio(0);

      // ---- band gather (shfl) + add ----
#pragma unroll
      for (int g = 0; g < 4; ++g) {
        float bp[5];
#pragma unroll
        for (int u5 = 0; u5 < 5; ++u5) bp[u5] = __shfl(sp[u5][g], gl4[g]);
#pragma unroll
        for (int tt = 0; tt < 4; ++tt)
          sc[tt][g] += cg[g] ? bp[tt + 1] : bp[tt];
      }
      // ---- scores -> LDS (D-frag write) ----
#pragma unroll
      for (int g = 0; g < 4; ++g)
#pragma unroll
        for (int tt = 0; tt < 4; ++tt)
          Psf[w][lg * 4 + g][tt * 16 + lr] = sc[tt][g];

      // ---- A-frag read: lane (lr,lg) holds row q=lr, k = kc*32+lg*8+j ----
      float zz[2][8];
#pragma unroll
      for (int kc = 0; kc < 2; ++kc)
#pragma unroll
        for (int h4 = 0; h4 < 2; ++h4) {
          float4 rv = *(const float4*)&Psf[w][lr][kc * 32 + lg * 8 + h4 * 4];
          zz[kc][h4 * 4 + 0] = rv.x; zz[kc][h4 * 4 + 1] = rv.y;
          zz[kc][h4 * 4 + 2] = rv.z; zz[kc][h4 * 4 + 3] = rv.w;
        }
      // ---- causal mask: only the diagonal tile ----
      if (kt == nt - 1) {
        int iglob = i0 + w * 16 + lr;
#pragma unroll
        for (int kc = 0; kc < 2; ++kc)
#pragma unroll
          for (int j = 0; j < 8; ++j)
            if (j0 + kc * 32 + lg * 8 + j > iglob) zz[kc][j] = -1e30f;
      }

      // ---- T13: speculative exp vs OLD max; pack; PV first ----
#pragma unroll
      for (int kc = 0; kc < 2; ++kc)
#pragma unroll
        for (int j = 0; j < 8; ++j) zz[kc][j] = __expf(zz[kc][j] - m_run);
      bf16x8 pf[2];
#pragma unroll
      for (int kc = 0; kc < 2; ++kc) {
        u32x4 pw;
#pragma unroll
        for (int j2 = 0; j2 < 4; ++j2)
          pw[j2] = cvtpk(zz[kc][j2 * 2], zz[kc][j2 * 2 + 1]);
        pf[kc] = __builtin_bit_cast(bf16x8, pw);
      }
      __builtin_amdgcn_s_setprio(1);
#pragma unroll
      for (int dt = 0; dt < 4; ++dt) {
#pragma unroll
        for (int kc = 0; kc < 2; ++kc) {
          bf16x8 vf = *(const bf16x8*)&Vtb[cur][(dt * 2 + kc) * 512 + l * 8];
          o_acc[dt] = __builtin_amdgcn_mfma_f32_16x16x32_bf16(pf[kc], vf, o_acc[dt], 0, 0, 0);
        }
      }
      __builtin_amdgcn_s_setprio(0);

      // ---- shadow reductions on e = exp(z - m_run) ----
      float s, em;
      {
        float a0 = zz[0][0] + zz[0][1], a1 = zz[0][2] + zz[0][3];
        float a2 = zz[0][4] + zz[0][5], a3 = zz[0][6] + zz[0][7];
        float a4 = zz[1][0] + zz[1][1], a5 = zz[1][2] + zz[1][3];
        float a6 = zz[1][4] + zz[1][5], a7 = zz[1][6] + zz[1][7];
        s = ((a0 + a1) + (a2 + a3)) + ((a4 + a5) + (a6 + a7));
        float m0 = fmax3(zz[0][0], zz[0][1], zz[0][2]);
        float m1 = fmax3(zz[0][3], zz[0][4], zz[0][5]);
        float m2 = fmax3(zz[0][6], zz[0][7], zz[1][0]);
        float m3 = fmax3(zz[1][1], zz[1][2], zz[1][3]);
        float m4 = fmax3(zz[1][4], zz[1][5], zz[1][6]);
        em = fmax3(m0, m1, zz[1][7]);
        em = fmax3(em, m2, m3);
        em = fmaxf(em, m4);
      }
      s += __shfl_xor(s, 16);
      s += __shfl_xor(s, 32);
      em = fmaxf(em, __shfl_xor(em, 16));
      em = fmaxf(em, __shfl_xor(em, 32));

      if (__all(em <= 2980.958f)) {   // max e <= e^8: keep old baseline
        l_run += s;
      } else {
        float lem = __logf(fmaxf(em, 1.f));
        float corr = __expf(-lem);          // exp(m_run - mnew), ==1 if em<=1
        m_run += lem;
        l_run = (l_run + s) * corr;
        float co[4];
#pragma unroll
        for (int g = 0; g < 4; ++g) co[g] = __shfl(corr, lg * 4 + g);
#pragma unroll
        for (int dt = 0; dt < 4; ++dt)
#pragma unroll
          for (int g = 0; g < 4; ++g) o_acc[dt][g] *= co[g];
      }

      __syncthreads();
      int stmp = sA; sA = sB; sB = sC; sC = stmp;
    }

    float ll[4];
#pragma unroll
    for (int g = 0; g < 4; ++g) ll[g] = __shfl(l_run, lg * 4 + g);
#pragma unroll
    for (int dt = 0; dt < 4; ++dt) {
      int col = h * 64 + dt * 16 + lr;
#pragma unroll
      for (int g = 0; g < 4; ++g) {
        int row = b * S_LEN + i0 + w * 16 + lg * 4 + g;
        out[(size_t)row * 1024 + col] = f2bf(o_acc[dt][g] / ll[g]);
      }
    }
  }
}

extern "C" void kernel_launch(void* const* d_in, const int* in_sizes, int n_in,
                              void* d_out, int out_size, void* d_ws, size_t ws_size,
                              hipStream_t stream) {
  const float* x    = (const float*)d_in[0];
  const float* Wqkv = (const float*)d_in[1];
  const float* Wout = (const float*)d_in[2];
  const float* Wpos = (const float*)d_in[3];
  const float* u    = (const float*)d_in[4];
  const float* v    = (const float*)d_in[5];
  const float* rel  = (const float*)d_in[6];
  float* out = (float*)d_out;

  u16* ws      = (u16*)d_ws;
  u16* xb      = ws;                      // (unused slot, kept for layout)
  u16* wqkvb   = xb + 4194304;            // 3072x1024
  u16* woutb   = wqkvb + 3145728;         // 1024x1024
  u16* wposb   = woutb + 1048576;         // 1024x1024
  u16* relb    = wposb + 1048576;         // 1024x1024
  u16* qkvb    = relb + 1048576;          // 4096x3072: cols 0-1023 = V^T, 1024-2047 = K
  u16* qcb     = qkvb + 12582912;         // 4096x1024
  u16* qpb     = qcb + 4194304;           // 4096x1024
  u16* relproj = qpb + 4194304;           // 1024x1024
  u16* attno   = relproj + 1048576;       // 4096x1024

  cvt_all<<<6144, 256, 0, stream>>>(Wqkv, Wout, Wpos, rel, wqkvb, woutb, wposb, relb);

  gemm_qkv_rel<<<896, 256, 0, stream>>>(x, wqkvb, qkvb, qcb, qpb, u, v, relb, wposb, relproj);
  attn_fwd<<<dim3(8, 64), 256, 0, stream>>>(qcb, qpb, qkvb, relproj, attno);
  gemm_out<<<dim3(64, 8), 256, 0, stream>>>(attno, woutb, out);
}

// Round 14
// 126.053 us; speedup vs baseline: 1.1228x; 1.1228x over previous
//
#include <hip/hip_runtime.h>

#define S_LEN 1024

typedef unsigned short u16;
using bf16x8 = __attribute__((ext_vector_type(8))) short;
using f32x4  = __attribute__((ext_vector_type(4))) float;
using u16x8  = __attribute__((ext_vector_type(8))) unsigned short;
using u16x4  = __attribute__((ext_vector_type(4))) unsigned short;
using u32x4  = __attribute__((ext_vector_type(4))) unsigned int;

__device__ __forceinline__ float bf2f(u16 b) {
  unsigned int u = ((unsigned int)b) << 16;
  return __builtin_bit_cast(float, u);
}
__device__ __forceinline__ u16 f2bf(float f) {
  unsigned int u = __builtin_bit_cast(unsigned int, f);
  unsigned int r = u + 0x7fffu + ((u >> 16) & 1u);
  return (u16)(r >> 16);
}
// packed RNE f32x2 -> bf16x2 (same rounding as f2bf)
__device__ __forceinline__ unsigned int cvtpk(float lo, float hi) {
  unsigned int r;
  asm("v_cvt_pk_bf16_f32 %0, %1, %2" : "=v"(r) : "v"(lo), "v"(hi));
  return r;
}
__device__ __forceinline__ float fmax3(float a, float b, float c) {
  return fmaxf(fmaxf(a, b), c);  // fuses to v_max3_f32
}

using gas_p = const __attribute__((address_space(1))) void*;
using las_p = __attribute__((address_space(3))) void*;
__device__ __forceinline__ void gload16(const void* g, void* l) {
  __builtin_amdgcn_global_load_lds((gas_p)g, (las_p)l, 16, 0, 0);
}

// ---------------- merged f32 -> bf16 conversion ----------------
__global__ __launch_bounds__(256) void cvt_all(const float* __restrict__ x,
    const float* __restrict__ wqkv, const float* __restrict__ wout,
    const float* __restrict__ wpos, const float* __restrict__ rel,
    u16* __restrict__ xb, u16* __restrict__ wqkvb, u16* __restrict__ woutb,
    u16* __restrict__ wposb, u16* __restrict__ relb) {
  int blk = blockIdx.x;
  const float* src; u16* dst; int base;
  if (blk < 4096)      { src = x;    dst = xb;    base = blk; }
  else if (blk < 7168) { src = wqkv; dst = wqkvb; base = blk - 4096; }
  else if (blk < 8192) { src = wout; dst = woutb; base = blk - 7168; }
  else if (blk < 9216) { src = wpos; dst = wposb; base = blk - 8192; }
  else                 { src = rel;  dst = relb;  base = blk - 9216; }
  int i = (base * 256 + threadIdx.x) * 4;
  float4 v = *(const float4*)(src + i);
  u16x4 o;
  o.x = f2bf(v.x); o.y = f2bf(v.y); o.z = f2bf(v.z); o.w = f2bf(v.w);
  *(u16x4*)(dst + i) = o;
}

// ---------------- fused QKV GEMM (768 blocks) + rel GEMM (128 blocks) ----------------
// Blocks 0..767: qkv = xb @ wqkvb^T with MODE2 epilogue (qc/qp scaled, k cols,
// v cols transposed into the q-hole). Blocks 768..895: relproj = relb @ wposb^T
// (bf16 out, BM=64). The rel blocks fill CUs during the QKV span instead of a
// separate serial dispatch (rel grid alone = 128 blocks = half the chip idle).
__global__ __launch_bounds__(256) void gemm_qkv_rel(
    const u16* __restrict__ xb, const u16* __restrict__ wqkvb,
    u16* __restrict__ qkvb, u16* __restrict__ qc, u16* __restrict__ qp,
    const float* __restrict__ uvec, const float* __restrict__ vvec,
    const u16* __restrict__ relb, const u16* __restrict__ wposb,
    u16* __restrict__ relproj) {
  __shared__ __align__(16) u16 As[2][128 * 32];
  __shared__ __align__(16) u16 Ws[2][128 * 32];
  const int t = threadIdx.x;
  const int w = t >> 6, l = t & 63;
  const int lr = l & 15, lg = l >> 4;
  const int flat = blockIdx.x;

  if (flat < 768) {
    // ---- QKV path: M=4096, N=3072, K=1024, BM=128, MI=4 ----
    const int xcd = flat & 7, idx = flat >> 3;
    const int bm = (xcd & 3) * 8 + (idx & 7);
    const int bn = (xcd >> 2) * 12 + (idx >> 3);
    const int wr = (w >> 1) * 64, wc = (w & 1) * 64;
    f32x4 acc[4][4];
#pragma unroll
    for (int mi = 0; mi < 4; ++mi)
#pragma unroll
      for (int ni = 0; ni < 4; ++ni) acc[mi][ni] = (f32x4){0.f, 0.f, 0.f, 0.f};
    const u16* Ab = xb + (size_t)bm * 128 * 1024;
    const u16* Wb = wqkvb + (size_t)bn * 128 * 1024;
    auto stage = [&](int k0, int buf) {
#pragma unroll
      for (int i = 0; i < 2; ++i) {
        int c = i * 256 + t;
        gload16(Ab + (size_t)(c >> 2) * 1024 + k0 + (c & 3) * 8, &As[buf][c * 8]);
      }
#pragma unroll
      for (int i = 0; i < 2; ++i) {
        int c = i * 256 + t;
        gload16(Wb + (size_t)(c >> 2) * 1024 + k0 + (c & 3) * 8, &Ws[buf][c * 8]);
      }
    };
    stage(0, 0);
    __syncthreads();
    for (int k0 = 0; k0 < 1024; k0 += 32) {
      const int cur = (k0 >> 5) & 1;
      if (k0 + 32 < 1024) stage(k0 + 32, cur ^ 1);
      bf16x8 af[4], wf[4];
#pragma unroll
      for (int mi = 0; mi < 4; ++mi)
        af[mi] = *(const bf16x8*)&As[cur][(wr + mi * 16 + lr) * 32 + lg * 8];
#pragma unroll
      for (int ni = 0; ni < 4; ++ni)
        wf[ni] = *(const bf16x8*)&Ws[cur][(wc + ni * 16 + lr) * 32 + lg * 8];
      __builtin_amdgcn_s_setprio(1);
#pragma unroll
      for (int mi = 0; mi < 4; ++mi)
#pragma unroll
        for (int ni = 0; ni < 4; ++ni)
          acc[mi][ni] = __builtin_amdgcn_mfma_f32_16x16x32_bf16(af[mi], wf[ni], acc[mi][ni], 0, 0, 0);
      __builtin_amdgcn_s_setprio(0);
      __syncthreads();
    }
#pragma unroll
    for (int mi = 0; mi < 4; ++mi)
#pragma unroll
      for (int ni = 0; ni < 4; ++ni) {
        int col = bn * 128 + wc + ni * 16 + lr;
        if (col < 1024) {
          float uu = uvec[col], vv = vvec[col];
#pragma unroll
          for (int g = 0; g < 4; ++g) {
            int row = bm * 128 + wr + mi * 16 + lg * 4 + g;
            qc[(size_t)row * 1024 + col] = f2bf((acc[mi][ni][g] + uu) * 0.125f);
            qp[(size_t)row * 1024 + col] = f2bf((acc[mi][ni][g] + vv) * 0.125f);
          }
        } else if (col < 2048) {
#pragma unroll
          for (int g = 0; g < 4; ++g) {
            int row = bm * 128 + wr + mi * 16 + lg * 4 + g;
            qkvb[(size_t)row * 3072 + col] = f2bf(acc[mi][ni][g]);
          }
        } else {
          int row0 = bm * 128 + wr + mi * 16 + lg * 4;
          int vrow = (row0 >> 10) * 1024 + (col - 2048);
          u16x4 tmp;
#pragma unroll
          for (int g = 0; g < 4; ++g) tmp[g] = f2bf(acc[mi][ni][g]);
          *(u16x4*)&qkvb[(size_t)vrow * 3072 + (row0 & 1023)] = tmp;
        }
      }
  } else {
    // ---- rel path: relproj = relb @ wposb^T, M=N=K=1024, BM=64, MI=2 ----
    const int r = flat - 768;
    const int bm = r & 15, bn = r >> 4;
    const int wr = (w >> 1) * 32, wc = (w & 1) * 64;
    f32x4 acc[2][4];
#pragma unroll
    for (int mi = 0; mi < 2; ++mi)
#pragma unroll
      for (int ni = 0; ni < 4; ++ni) acc[mi][ni] = (f32x4){0.f, 0.f, 0.f, 0.f};
    const u16* Ab = relb + (size_t)bm * 64 * 1024;
    const u16* Wb = wposb + (size_t)bn * 128 * 1024;
    auto stage = [&](int k0, int buf) {
      {
        int c = t;
        gload16(Ab + (size_t)(c >> 2) * 1024 + k0 + (c & 3) * 8, &As[buf][c * 8]);
      }
#pragma unroll
      for (int i = 0; i < 2; ++i) {
        int c = i * 256 + t;
        gload16(Wb + (size_t)(c >> 2) * 1024 + k0 + (c & 3) * 8, &Ws[buf][c * 8]);
      }
    };
    stage(0, 0);
    __syncthreads();
    for (int k0 = 0; k0 < 1024; k0 += 32) {
      const int cur = (k0 >> 5) & 1;
      if (k0 + 32 < 1024) stage(k0 + 32, cur ^ 1);
      bf16x8 af[2], wf[4];
#pragma unroll
      for (int mi = 0; mi < 2; ++mi)
        af[mi] = *(const bf16x8*)&As[cur][(wr + mi * 16 + lr) * 32 + lg * 8];
#pragma unroll
      for (int ni = 0; ni < 4; ++ni)
        wf[ni] = *(const bf16x8*)&Ws[cur][(wc + ni * 16 + lr) * 32 + lg * 8];
      __builtin_amdgcn_s_setprio(1);
#pragma unroll
      for (int mi = 0; mi < 2; ++mi)
#pragma unroll
        for (int ni = 0; ni < 4; ++ni)
          acc[mi][ni] = __builtin_amdgcn_mfma_f32_16x16x32_bf16(af[mi], wf[ni], acc[mi][ni], 0, 0, 0);
      __builtin_amdgcn_s_setprio(0);
      __syncthreads();
    }
#pragma unroll
    for (int mi = 0; mi < 2; ++mi)
#pragma unroll
      for (int ni = 0; ni < 4; ++ni) {
        int col = bn * 128 + wc + ni * 16 + lr;
#pragma unroll
        for (int g = 0; g < 4; ++g) {
          int row = bm * 64 + wr + mi * 16 + lg * 4 + g;
          relproj[(size_t)row * 1024 + col] = f2bf(acc[mi][ni][g]);
        }
      }
  }
}

// ---------------- out-proj GEMM: out = attno @ woutb^T (f32 out) ----------------
// BM=64, grid(64,8) -> 512 blocks; SWZ3: each XCD owns one 128-col wout panel.
__global__ __launch_bounds__(256) void gemm_out(const u16* __restrict__ A,
    const u16* __restrict__ W, float* __restrict__ Yf) {
  __shared__ __align__(16) u16 As[2][64 * 32];
  __shared__ __align__(16) u16 Ws[2][128 * 32];
  const int t = threadIdx.x;
  const int w = t >> 6, l = t & 63;
  const int lr = l & 15, lg = l >> 4;
  const int flat = (int)blockIdx.y * 64 + (int)blockIdx.x;
  const int bn = flat & 7, bm = flat >> 3;
  const int wr = (w >> 1) * 32, wc = (w & 1) * 64;
  f32x4 acc[2][4];
#pragma unroll
  for (int mi = 0; mi < 2; ++mi)
#pragma unroll
    for (int ni = 0; ni < 4; ++ni) acc[mi][ni] = (f32x4){0.f, 0.f, 0.f, 0.f};
  const u16* Ab = A + (size_t)bm * 64 * 1024;
  const u16* Wb = W + (size_t)bn * 128 * 1024;
  auto stage = [&](int k0, int buf) {
    {
      int c = t;
      gload16(Ab + (size_t)(c >> 2) * 1024 + k0 + (c & 3) * 8, &As[buf][c * 8]);
    }
#pragma unroll
    for (int i = 0; i < 2; ++i) {
      int c = i * 256 + t;
      gload16(Wb + (size_t)(c >> 2) * 1024 + k0 + (c & 3) * 8, &Ws[buf][c * 8]);
    }
  };
  stage(0, 0);
  __syncthreads();
  for (int k0 = 0; k0 < 1024; k0 += 32) {
    const int cur = (k0 >> 5) & 1;
    if (k0 + 32 < 1024) stage(k0 + 32, cur ^ 1);
    bf16x8 af[2], wf[4];
#pragma unroll
    for (int mi = 0; mi < 2; ++mi)
      af[mi] = *(const bf16x8*)&As[cur][(wr + mi * 16 + lr) * 32 + lg * 8];
#pragma unroll
    for (int ni = 0; ni < 4; ++ni)
      wf[ni] = *(const bf16x8*)&Ws[cur][(wc + ni * 16 + lr) * 32 + lg * 8];
    __builtin_amdgcn_s_setprio(1);
#pragma unroll
    for (int mi = 0; mi < 2; ++mi)
#pragma unroll
      for (int ni = 0; ni < 4; ++ni)
        acc[mi][ni] = __builtin_amdgcn_mfma_f32_16x16x32_bf16(af[mi], wf[ni], acc[mi][ni], 0, 0, 0);
    __builtin_amdgcn_s_setprio(0);
    __syncthreads();
  }
#pragma unroll
  for (int mi = 0; mi < 2; ++mi)
#pragma unroll
    for (int ni = 0; ni < 4; ++ni) {
      int col = bn * 128 + wc + ni * 16 + lr;
#pragma unroll
      for (int g = 0; g < 4; ++g) {
        int row = bm * 64 + wr + mi * 16 + lg * 4 + g;
        Yf[(size_t)row * 1024 + col] = acc[mi][ni][g];
      }
    }
}

// ---------------- fused causal attention with TXL rel-shift (v9, proven) ----------------
__global__ __launch_bounds__(256) void attn_fwd(
    const u16* __restrict__ qcb, const u16* __restrict__ qpb,
    const u16* __restrict__ qkv, const u16* __restrict__ relp,
    u16* __restrict__ out) {
  __shared__ __align__(16) u16 Ksb[2][4096];
  __shared__ __align__(16) u16 Vtb[2][4096];
  __shared__ __align__(16) u16 Rs3[3][4096];
  __shared__ __align__(16) float Psf[4][16][68];

  const int flat = (int)blockIdx.y * 8 + (int)blockIdx.x;
  const int wg = (flat & 7) * 64 + (flat >> 3);
  const int sub = wg & 7;
  const int bh = wg >> 3;
  const int b = bh >> 4, h = bh & 15;
  const int t = threadIdx.x;
  const int w = t >> 6, l = t & 63;
  const int lr = l & 15, lg = l >> 4;

  const u16* Kg = qkv + (size_t)b * S_LEN * 3072 + 1024 + h * 64;
  const u16* Vg = qkv + (size_t)bh * 64 * 3072;  // V^T rows in the q-hole
  const u16* Rg = relp + h * 64;

  int gl4[4], cg[4];
#pragma unroll
  for (int g = 0; g < 4; ++g) {
    int ql = lg * 4 + g;
    gl4[g] = (l & 48) | ((lr - ql - 1) & 15);
    cg[g] = (lr > ql) ? 1 : 0;
  }

  for (int half = 0; half < 2; ++half) {
    const int qt = half ? sub : (15 - sub);
    const int i0 = qt * 64;
    const int nt = qt + 1;

    bf16x8 qcf[2], qpf[2];
    {
      size_t qoff = (size_t)(b * S_LEN + i0 + w * 16 + lr) * 1024 + h * 64;
      qcf[0] = *(const bf16x8*)(qcb + qoff + lg * 8);
      qcf[1] = *(const bf16x8*)(qcb + qoff + 32 + lg * 8);
      qpf[0] = *(const bf16x8*)(qpb + qoff + lg * 8);
      qpf[1] = *(const bf16x8*)(qpb + qoff + 32 + lg * 8);
    }

    auto stage_k = [&](int j0s, int buf) {
#pragma unroll
      for (int i = 0; i < 2; ++i) {
        int bK = i * 4 + w;
        int ttk = bK >> 1, kc = bK & 1;
        gload16(Kg + (size_t)(j0s + ttk * 16 + lr) * 3072 + kc * 32 + lg * 8,
                &Ksb[buf][bK * 512 + l * 8]);
      }
    };
    auto stage_v = [&](int j0s, int buf) {
#pragma unroll
      for (int i = 0; i < 2; ++i) {
        int bV = i * 4 + w;
        int dt = bV >> 1, kc = bV & 1;
        gload16(Vg + (size_t)(dt * 16 + lr) * 3072 + j0s + kc * 32 + lg * 8,
                &Vtb[buf][bV * 512 + l * 8]);
      }
    };
    auto stage_rchunk = [&](int Gloc, int slot) {
      int Gg = 15 - qt + Gloc;
#pragma unroll
      for (int i = 0; i < 2; ++i) {
        int bR = i * 4 + w;
        int btc = bR >> 1, kc = bR & 1;
        int r = Gg * 64 + btc * 16 + lr;
        r = r > S_LEN - 1 ? S_LEN - 1 : r;
        gload16(Rg + (size_t)r * 1024 + kc * 32 + lg * 8,
                &Rs3[slot][bR * 512 + l * 8]);
      }
    };

    float m_run = 0.f, l_run = 0.f;   // T13: finite baseline (scores ~ +-12)
    f32x4 o_acc[4];
#pragma unroll
    for (int dt = 0; dt < 4; ++dt) o_acc[dt] = (f32x4){0.f, 0.f, 0.f, 0.f};

    stage_k(0, 0);
    stage_v(0, 0);
    stage_rchunk(0, 0);
    stage_rchunk(1, 1);
    __syncthreads();

    int sA = 0, sB = 1, sC = 2;
    for (int kt = 0; kt < nt; ++kt) {
      const int cur = kt & 1, nxt = cur ^ 1;
      const int j0 = kt * 64;
      const int have_nxt = (kt + 1 < nt);
      if (have_nxt) {
        stage_k(j0 + 64, nxt);
        stage_v(j0 + 64, nxt);
        stage_rchunk(kt + 2, sC);
      }

      // ---- Sc = qc @ K^T ----
      f32x4 sc[4];
      __builtin_amdgcn_s_setprio(1);
#pragma unroll
      for (int tt = 0; tt < 4; ++tt) {
        sc[tt] = (f32x4){0.f, 0.f, 0.f, 0.f};
#pragma unroll
        for (int kc = 0; kc < 2; ++kc) {
          bf16x8 kf = *(const bf16x8*)&Ksb[cur][(tt * 2 + kc) * 512 + l * 8];
          sc[tt] = __builtin_amdgcn_mfma_f32_16x16x32_bf16(qcf[kc], kf, sc[tt], 0, 0, 0);
        }
      }
      // ---- Sp band (5 tiles per wave) ----
      f32x4 sp[5];
#pragma unroll
      for (int u5 = 0; u5 < 5; ++u5) {
        int bt = 3 - w + u5;
        const u16* rb = (bt & 4) ? &Rs3[sB][0] : &Rs3[sA][0];
        int btc = bt & 3;
        sp[u5] = (f32x4){0.f, 0.f, 0.f, 0.f};
#pragma unroll
        for (int kc = 0; kc < 2; ++kc) {
          bf16x8 rf = *(const bf16x8*)&rb[(btc * 2 + kc) * 512 + l * 8];
          sp[u5] = __builtin_amdgcn_mfma_f32_16x16x32_bf16(qpf[kc], rf, sp[u5], 0, 0, 0);
        }
      }
      __builtin_amdgcn_s_setprio(0);

      // ---- band gather (shfl) + add ----
#pragma unroll
      for (int g = 0; g < 4; ++g) {
        float bp[5];
#pragma unroll
        for (int u5 = 0; u5 < 5; ++u5) bp[u5] = __shfl(sp[u5][g], gl4[g]);
#pragma unroll
        for (int tt = 0; tt < 4; ++tt)
          sc[tt][g] += cg[g] ? bp[tt + 1] : bp[tt];
      }
      // ---- scores -> LDS (D-frag write) ----
#pragma unroll
      for (int g = 0; g < 4; ++g)
#pragma unroll
        for (int tt = 0; tt < 4; ++tt)
          Psf[w][lg * 4 + g][tt * 16 + lr] = sc[tt][g];

      // ---- A-frag read: lane (lr,lg) holds row q=lr, k = kc*32+lg*8+j ----
      float zz[2][8];
#pragma unroll
      for (int kc = 0; kc < 2; ++kc)
#pragma unroll
        for (int h4 = 0; h4 < 2; ++h4) {
          float4 rv = *(const float4*)&Psf[w][lr][kc * 32 + lg * 8 + h4 * 4];
          zz[kc][h4 * 4 + 0] = rv.x; zz[kc][h4 * 4 + 1] = rv.y;
          zz[kc][h4 * 4 + 2] = rv.z; zz[kc][h4 * 4 + 3] = rv.w;
        }
      // ---- causal mask: only the diagonal tile ----
      if (kt == nt - 1) {
        int iglob = i0 + w * 16 + lr;
#pragma unroll
        for (int kc = 0; kc < 2; ++kc)
#pragma unroll
          for (int j = 0; j < 8; ++j)
            if (j0 + kc * 32 + lg * 8 + j > iglob) zz[kc][j] = -1e30f;
      }

      // ---- T13: speculative exp vs OLD max; pack; PV first ----
#pragma unroll
      for (int kc = 0; kc < 2; ++kc)
#pragma unroll
        for (int j = 0; j < 8; ++j) zz[kc][j] = __expf(zz[kc][j] - m_run);
      bf16x8 pf[2];
#pragma unroll
      for (int kc = 0; kc < 2; ++kc) {
        u32x4 pw;
#pragma unroll
        for (int j2 = 0; j2 < 4; ++j2)
          pw[j2] = cvtpk(zz[kc][j2 * 2], zz[kc][j2 * 2 + 1]);
        pf[kc] = __builtin_bit_cast(bf16x8, pw);
      }
      __builtin_amdgcn_s_setprio(1);
#pragma unroll
      for (int dt = 0; dt < 4; ++dt) {
#pragma unroll
        for (int kc = 0; kc < 2; ++kc) {
          bf16x8 vf = *(const bf16x8*)&Vtb[cur][(dt * 2 + kc) * 512 + l * 8];
          o_acc[dt] = __builtin_amdgcn_mfma_f32_16x16x32_bf16(pf[kc], vf, o_acc[dt], 0, 0, 0);
        }
      }
      __builtin_amdgcn_s_setprio(0);

      // ---- shadow reductions on e = exp(z - m_run) ----
      float s, em;
      {
        float a0 = zz[0][0] + zz[0][1], a1 = zz[0][2] + zz[0][3];
        float a2 = zz[0][4] + zz[0][5], a3 = zz[0][6] + zz[0][7];
        float a4 = zz[1][0] + zz[1][1], a5 = zz[1][2] + zz[1][3];
        float a6 = zz[1][4] + zz[1][5], a7 = zz[1][6] + zz[1][7];
        s = ((a0 + a1) + (a2 + a3)) + ((a4 + a5) + (a6 + a7));
        float m0 = fmax3(zz[0][0], zz[0][1], zz[0][2]);
        float m1 = fmax3(zz[0][3], zz[0][4], zz[0][5]);
        float m2 = fmax3(zz[0][6], zz[0][7], zz[1][0]);
        float m3 = fmax3(zz[1][1], zz[1][2], zz[1][3]);
        float m4 = fmax3(zz[1][4], zz[1][5], zz[1][6]);
        em = fmax3(m0, m1, zz[1][7]);
        em = fmax3(em, m2, m3);
        em = fmaxf(em, m4);
      }
      s += __shfl_xor(s, 16);
      s += __shfl_xor(s, 32);
      em = fmaxf(em, __shfl_xor(em, 16));
      em = fmaxf(em, __shfl_xor(em, 32));

      if (__all(em <= 2980.958f)) {   // max e <= e^8: keep old baseline
        l_run += s;
      } else {
        float lem = __logf(fmaxf(em, 1.f));
        float corr = __expf(-lem);          // exp(m_run - mnew), ==1 if em<=1
        m_run += lem;
        l_run = (l_run + s) * corr;
        float co[4];
#pragma unroll
        for (int g = 0; g < 4; ++g) co[g] = __shfl(corr, lg * 4 + g);
#pragma unroll
        for (int dt = 0; dt < 4; ++dt)
#pragma unroll
          for (int g = 0; g < 4; ++g) o_acc[dt][g] *= co[g];
      }

      __syncthreads();
      int stmp = sA; sA = sB; sB = sC; sC = stmp;
    }

    float ll[4];
#pragma unroll
    for (int g = 0; g < 4; ++g) ll[g] = __shfl(l_run, lg * 4 + g);
#pragma unroll
    for (int dt = 0; dt < 4; ++dt) {
      int col = h * 64 + dt * 16 + lr;
#pragma unroll
      for (int g = 0; g < 4; ++g) {
        int row = b * S_LEN + i0 + w * 16 + lg * 4 + g;
        out[(size_t)row * 1024 + col] = f2bf(o_acc[dt][g] / ll[g]);
      }
    }
  }
}

extern "C" void kernel_launch(void* const* d_in, const int* in_sizes, int n_in,
                              void* d_out, int out_size, void* d_ws, size_t ws_size,
                              hipStream_t stream) {
  const float* x    = (const float*)d_in[0];
  const float* Wqkv = (const float*)d_in[1];
  const float* Wout = (const float*)d_in[2];
  const float* Wpos = (const float*)d_in[3];
  const float* u    = (const float*)d_in[4];
  const float* v    = (const float*)d_in[5];
  const float* rel  = (const float*)d_in[6];
  float* out = (float*)d_out;

  u16* ws      = (u16*)d_ws;
  u16* xb      = ws;                      // 4096x1024
  u16* wqkvb   = xb + 4194304;            // 3072x1024
  u16* woutb   = wqkvb + 3145728;         // 1024x1024
  u16* wposb   = woutb + 1048576;         // 1024x1024
  u16* relb    = wposb + 1048576;         // 1024x1024
  u16* qkvb    = relb + 1048576;          // 4096x3072: cols 0-1023 = V^T, 1024-2047 = K
  u16* qcb     = qkvb + 12582912;         // 4096x1024
  u16* qpb     = qcb + 4194304;           // 4096x1024
  u16* relproj = qpb + 4194304;           // 1024x1024
  u16* attno   = relproj + 1048576;       // 4096x1024

  cvt_all<<<10240, 256, 0, stream>>>(x, Wqkv, Wout, Wpos, rel, xb, wqkvb, woutb, wposb, relb);

  gemm_qkv_rel<<<896, 256, 0, stream>>>(xb, wqkvb, qkvb, qcb, qpb, u, v, relb, wposb, relproj);
  attn_fwd<<<dim3(8, 64), 256, 0, stream>>>(qcb, qpb, qkvb, relproj, attno);
  gemm_out<<<dim3(64, 8), 256, 0, stream>>>(attno, woutb, out);
}